// Round 1
// baseline (397.052 us; speedup 1.0000x reference)
//
#include <hip/hip_runtime.h>
#include <math.h>

#define NB 64
#define CC 64
#define TT 300
#define VV 25
#define SS 3
#define TB 4
#define COLS (TB*VV)      // 100
#define TBLK (TT/TB)      // 75

// ws layout (floats): [0:64] gsum, [64:128] gsumsq, [128:192] scale, [192:256] shift

__global__ __launch_bounds__(256) void gcn_main_kernel(
    const float* __restrict__ x, const float* __restrict__ PA,
    const float* __restrict__ Wc, const float* __restrict__ bc,
    float* __restrict__ yout, float* __restrict__ stats)
{
    __shared__ float xs[CC][COLS];     // 25600 B
    __shared__ float zs[CC][TB][28];   // 28672 B (rows padded to 28 floats, 16B aligned)
    __shared__ float As[SS][VV][28];   // 8400 B

    const int bx  = blockIdx.x;
    const int n   = bx / TBLK;
    const int t0  = (bx % TBLK) * TB;
    const int tid = threadIdx.x;

    // --- normalize adjacency into LDS (tiny; redundant per block) ---
    if (tid < SS * VV) {
        const int s = tid / VV, w = tid % VV;
        const float* col = PA + (size_t)s * VV * VV + w;  // stride VV down the column
        float ssum = 0.f;
        #pragma unroll
        for (int v = 0; v < VV; ++v) { float p = col[v * VV]; ssum = fmaf(p, p, ssum); }
        const float inv = 1.f / (sqrtf(ssum) + 1e-4f);
        #pragma unroll
        for (int v = 0; v < VV; ++v) As[s][v][w] = col[v * VV] * inv;
    }

    // --- stage x tile: x[n, c, t0:t0+TB, :] -> xs[c][0:100] (float4, aligned) ---
    const float* xbase = x + ((size_t)n * CC * TT + t0) * VV;
    for (int i4 = tid; i4 < CC * COLS / 4; i4 += 256) {
        const int c = i4 / (COLS / 4);
        const int j = i4 % (COLS / 4);
        reinterpret_cast<float4*>(&xs[c][0])[j] =
            reinterpret_cast<const float4*>(xbase + (size_t)c * TT * VV)[j];
    }
    __syncthreads();

    const int hi = tid >> 2;   // stage A: c index; stage B: o index
    const int t  = tid & 3;

    float acc[VV];
    #pragma unroll
    for (int w = 0; w < VV; ++w) acc[w] = 0.f;

    for (int s = 0; s < SS; ++s) {
        // ---- stage A: za[w] = sum_v xs[hi][t*25+v] * A[s][v][w]  (regs) ----
        float za[VV];
        #pragma unroll
        for (int w = 0; w < VV; ++w) za[w] = 0.f;
        const float* xrow = &xs[hi][t * VV];
        #pragma unroll 5
        for (int v = 0; v < VV; ++v) {
            const float xv = xrow[v];
            const float4* arow = reinterpret_cast<const float4*>(&As[s][v][0]);
            #pragma unroll
            for (int j = 0; j < 6; ++j) {
                float4 a4 = arow[j];
                za[4*j+0] = fmaf(xv, a4.x, za[4*j+0]);
                za[4*j+1] = fmaf(xv, a4.y, za[4*j+1]);
                za[4*j+2] = fmaf(xv, a4.z, za[4*j+2]);
                za[4*j+3] = fmaf(xv, a4.w, za[4*j+3]);
            }
            za[24] = fmaf(xv, As[s][v][24], za[24]);
        }

        __syncthreads();   // previous stage B done reading zs
        float* zrow = &zs[hi][t][0];
        #pragma unroll
        for (int j = 0; j < 6; ++j) {
            float4 q = make_float4(za[4*j+0], za[4*j+1], za[4*j+2], za[4*j+3]);
            reinterpret_cast<float4*>(zrow)[j] = q;
        }
        zrow[24] = za[24];
        __syncthreads();

        // ---- stage B: acc[w] += sum_c Wc[s][hi][c] * zs[c][t][w] ----
        const float* wrow = Wc + ((size_t)s * CC + hi) * CC;
        #pragma unroll 4
        for (int c = 0; c < CC; ++c) {
            const float wv = wrow[c];
            const float4* zr = reinterpret_cast<const float4*>(&zs[c][t][0]);
            #pragma unroll
            for (int j = 0; j < 6; ++j) {
                float4 q = zr[j];
                acc[4*j+0] = fmaf(wv, q.x, acc[4*j+0]);
                acc[4*j+1] = fmaf(wv, q.y, acc[4*j+1]);
                acc[4*j+2] = fmaf(wv, q.z, acc[4*j+2]);
                acc[4*j+3] = fmaf(wv, q.w, acc[4*j+3]);
            }
            acc[24] = fmaf(wv, zs[c][t][24], acc[24]);
        }
    }

    // ---- epilogue: bias, store unnormalized y, channel sums ----
    const float bias = bc[hi] + bc[CC + hi] + bc[2 * CC + hi];
    float s1 = 0.f, s2 = 0.f;
    float* orow = yout + ((size_t)(n * CC + hi) * TT + t0 + t) * VV;
    #pragma unroll
    for (int w = 0; w < VV; ++w) {
        const float vY = acc[w] + bias;
        orow[w] = vY;
        s1 += vY;
        s2 = fmaf(vY, vY, s2);
    }
    // reduce across the 4 threads (t=0..3) sharing channel hi (adjacent lanes)
    s1 += __shfl_xor(s1, 1); s1 += __shfl_xor(s1, 2);
    s2 += __shfl_xor(s2, 1); s2 += __shfl_xor(s2, 2);
    if ((tid & 3) == 0) {
        atomicAdd(&stats[hi], s1);
        atomicAdd(&stats[64 + hi], s2);
    }
}

__global__ void gcn_finalize_kernel(const float* __restrict__ gamma,
                                    const float* __restrict__ beta,
                                    float* __restrict__ stats)
{
    const int o = threadIdx.x;
    if (o < CC) {
        const float cnt = (float)(NB * TT * VV);   // 480000
        const float mean = stats[o] / cnt;
        const float var  = stats[64 + o] / cnt - mean * mean;
        const float sc   = gamma[o] * rsqrtf(var + 1e-5f);
        stats[128 + o] = sc;
        stats[192 + o] = beta[o] - mean * sc;
    }
}

__global__ __launch_bounds__(256) void gcn_bn_relu_kernel(
    const float* __restrict__ x, float* __restrict__ y,
    const float* __restrict__ stats)
{
    const int total4 = NB * CC * TT * VV / 4;   // 7,680,000
    const int per_c4 = TT * VV / 4;             // 1875
    for (int i = blockIdx.x * 256 + threadIdx.x; i < total4; i += gridDim.x * 256) {
        const int c = (i / per_c4) & (CC - 1);
        const float sc = stats[128 + c];
        const float sh = stats[192 + c];
        float4 yv = reinterpret_cast<float4*>(y)[i];
        float4 xv = reinterpret_cast<const float4*>(x)[i];
        float4 r;
        r.x = fmaxf(fmaf(yv.x, sc, sh) + xv.x, 0.f);
        r.y = fmaxf(fmaf(yv.y, sc, sh) + xv.y, 0.f);
        r.z = fmaxf(fmaf(yv.z, sc, sh) + xv.z, 0.f);
        r.w = fmaxf(fmaf(yv.w, sc, sh) + xv.w, 0.f);
        reinterpret_cast<float4*>(y)[i] = r;
    }
}

extern "C" void kernel_launch(void* const* d_in, const int* in_sizes, int n_in,
                              void* d_out, int out_size, void* d_ws, size_t ws_size,
                              hipStream_t stream)
{
    const float* x     = (const float*)d_in[0];
    const float* PA    = (const float*)d_in[1];
    const float* Wc    = (const float*)d_in[2];
    const float* bc    = (const float*)d_in[3];
    const float* gamma = (const float*)d_in[4];
    const float* beta  = (const float*)d_in[5];
    float* out   = (float*)d_out;
    float* stats = (float*)d_ws;

    hipMemsetAsync(stats, 0, 256 * sizeof(float), stream);
    gcn_main_kernel<<<NB * TBLK, 256, 0, stream>>>(x, PA, Wc, bc, out, stats);
    gcn_finalize_kernel<<<1, 64, 0, stream>>>(gamma, beta, stats);
    gcn_bn_relu_kernel<<<2048, 256, 0, stream>>>(x, out, stats);
}